// Round 10
// baseline (230.917 us; speedup 1.0000x reference)
//
#include <hip/hip_runtime.h>
#include <math.h>

// Problem constants
constexpr int B = 8;
constexpr int D = 256;     // model dim
constexpr int C = 1024;    // expanded channels
constexpr int H = 32, W = 32;
constexpr int P = H * W;            // 1024 spatial positions
constexpr int M = B * P;            // 8192 rows
constexpr float EPS = 1e-5f;

typedef unsigned short u16;
typedef unsigned int u32;
typedef __attribute__((ext_vector_type(8))) short short8;
typedef __attribute__((ext_vector_type(4))) float floatx4;

// ---------------- workspace layout (in floats) ----------------
// zero-initialized accumulator region (zeroed by cvt kernel)
constexpr size_t WS_CHSUM1 = 0;                  // 1024
constexpr size_t WS_CHSQ1  = 1024;               // 1024
constexpr size_t WS_GAPSUM = 2048;               // 8192
constexpr size_t WS_CHSUM3 = 10240;              // 256
constexpr size_t WS_CHSQ3  = 10496;              // 256
constexpr size_t WS_CHSUM2 = 10752;              // 1024
constexpr size_t WS_CHSQ2  = 11776;              // 1024
constexpr size_t WS_BSUM2  = 12800;              // 8192
constexpr size_t WS_UMAX2  = 20992;              // 8192 (u32 keys)
constexpr size_t WS_UMAXN2 = 29184;              // 8192 (u32 keys of -min)
constexpr size_t WS_ACC_COUNT = 37376;
// non-zeroed
constexpr size_t WS_SCALE1 = 37376;              // 1024
constexpr size_t WS_SHIFT1 = 38400;              // 1024
constexpr size_t WS_KW     = 39424;              // 256 (72 used)
constexpr size_t WS_SCALE2 = 39680;              // 1024
constexpr size_t WS_SHIFT2 = 40704;              // 1024
constexpr size_t WS_SATT   = 41728;              // 8192
constexpr size_t WS_AVGO   = 49920;              // 8192
constexpr size_t WS_MAXO   = 58112;              // 8192
constexpr size_t WS_SP     = 66304;              // 8192
constexpr size_t WS_PRE    = 74496;              // 2097152
constexpr size_t WS_T1B    = 2171648;            // bf16 t1 (4194304 floats)
constexpr size_t WS_T2B    = 6365952;            // bf16 t2
constexpr size_t WS_XB     = 10560256;           // bf16 x
constexpr size_t WS_W1B    = 11608832;
constexpr size_t WS_PWB    = 11739904;
constexpr size_t WS_YB     = 11870976;           // bf16 y
// total = 16065280 floats = 64.3 MB

__device__ __forceinline__ float gelu_exact(float v) {
    return 0.5f * v * (1.0f + erff(v * 0.70710678118654752440f));
}

__device__ __forceinline__ u16 f2bf(float f) {
    u32 u = __float_as_uint(f);
    u += 0x7fff + ((u >> 16) & 1);   // round-to-nearest-even
    return (u16)(u >> 16);
}

__device__ __forceinline__ float bf2f(u16 v) {
    return __uint_as_float(((u32)v) << 16);
}

// order-preserving float->u32 key: unsigned compare order == float order
__device__ __forceinline__ u32 fkey(float f) {
    u32 u = __float_as_uint(f);
    return (u & 0x80000000u) ? ~u : (u | 0x80000000u);
}
__device__ __forceinline__ float fkeyinv(u32 k) {
    return __uint_as_float((k & 0x80000000u) ? (k ^ 0x80000000u) : ~k);
}

// ---------------- K0: zero accumulators + cast fp32 -> bf16 for x, w1, pw ----------------
__global__ __launch_bounds__(256) void cvt_all_kernel(const float* __restrict__ x,
                                                      const float* __restrict__ w1,
                                                      const float* __restrict__ pw,
                                                      u16* __restrict__ xb,
                                                      u16* __restrict__ w1b,
                                                      u16* __restrict__ pwb,
                                                      float* __restrict__ acc_zero) {
    const int i = blockIdx.x * 256 + threadIdx.x;
    if (i < (int)WS_ACC_COUNT) acc_zero[i] = 0.f;   // 0x0 == fkey floor for max-keys too
    const float* src;
    u16* dst;
    int off;
    if (i < 524288)      { src = x;  dst = xb;  off = i; }
    else if (i < 589824) { src = w1; dst = w1b; off = i - 524288; }
    else                 { src = pw; dst = pwb; off = i - 589824; }
    const float4 v = *(const float4*)(src + (size_t)off * 4);
    uint2 o;
    o.x = ((u32)f2bf(v.x)) | ((u32)f2bf(v.y) << 16);
    o.y = ((u32)f2bf(v.z)) | ((u32)f2bf(v.w) << 16);
    *(uint2*)(dst + (size_t)off * 4) = o;
}

// ---------------- MFMA bf16 GEMM + fused epilogue + fused column stats (R7-proven) ----------------
template<int KD, int EPI, int NS, int MB, int NB>
__global__ __launch_bounds__(256) void mfma_gemm_kernel(
    const u16* __restrict__ A,
    const u16* __restrict__ Bw,
    const float* __restrict__ bias,
    const float* __restrict__ rowscale,
    void* __restrict__ outv,
    float* __restrict__ csum,
    float* __restrict__ csq,
    float* __restrict__ gsum)
{
    constexpr int MI = MB / 32;
    constexpr int NJ = NB / 32;
    extern __shared__ u16 smem[];
    u16* As = smem;
    u16* Bs = smem + MB * 32;
    const int t = threadIdx.x;
    const int lane = t & 63;
    const int row0 = blockIdx.y * MB;
    const int col0 = blockIdx.x * NB;
    const int wv = t >> 6;
    const int wrow = (wv >> 1) * (MB / 2);
    const int wcol = (wv & 1) * (NB / 2);
    const int lm = lane & 15;
    const int lk8 = (lane >> 4) * 8;
    const int srow = t >> 2;
    const int scol = (t & 3) * 8;
    const u16* gA0 = A + (size_t)(row0 + srow) * KD + scol;
    const u16* gA1 = A + (size_t)(row0 + 64 + srow) * KD + scol;
    const u16* gB0 = Bw + (size_t)(col0 + srow) * KD + scol;
    const floatx4 zero = {0.f, 0.f, 0.f, 0.f};
    floatx4 acc[MI][NJ];
#pragma unroll
    for (int i = 0; i < MI; ++i)
#pragma unroll
        for (int j = 0; j < NJ; ++j) acc[i][j] = zero;
    for (int k0 = 0; k0 < KD; k0 += 32) {
        __builtin_amdgcn_global_load_lds(
            (const __attribute__((address_space(1))) void*)(gA0 + k0),
            (__attribute__((address_space(3))) void*)(As + t * 8), 16, 0, 0);
        if (MB == 128)
            __builtin_amdgcn_global_load_lds(
                (const __attribute__((address_space(1))) void*)(gA1 + k0),
                (__attribute__((address_space(3))) void*)(As + 2048 + t * 8), 16, 0, 0);
        __builtin_amdgcn_global_load_lds(
            (const __attribute__((address_space(1))) void*)(gB0 + k0),
            (__attribute__((address_space(3))) void*)(Bs + t * 8), 16, 0, 0);
        __syncthreads();
        short8 af[MI], bf[NJ];
#pragma unroll
        for (int i = 0; i < MI; ++i)
            af[i] = *(const short8*)(As + (wrow + i * 16 + lm) * 32 + lk8);
#pragma unroll
        for (int j = 0; j < NJ; ++j)
            bf[j] = *(const short8*)(Bs + (wcol + j * 16 + lm) * 32 + lk8);
#pragma unroll
        for (int i = 0; i < MI; ++i)
#pragma unroll
            for (int j = 0; j < NJ; ++j)
                acc[i][j] = __builtin_amdgcn_mfma_f32_16x16x32_bf16(af[i], bf[j], acc[i][j], 0, 0, 0);
        __syncthreads();
    }
    float colsum[NJ], colsq[NJ];
#pragma unroll
    for (int j = 0; j < NJ; ++j) { colsum[j] = 0.f; colsq[j] = 0.f; }
    if (EPI == 0) {
        u16* Cs = smem;
#pragma unroll
        for (int i = 0; i < MI; ++i) {
#pragma unroll
            for (int r = 0; r < 4; ++r) {
                const int lrow = wrow + i * 16 + (lane >> 4) * 4 + r;
#pragma unroll
                for (int j = 0; j < NJ; ++j) {
                    const int lcol = wcol + j * 16 + lm;
                    const float tv = gelu_exact(acc[i][j][r] + bias[col0 + lcol]);
                    Cs[lrow * NB + lcol] = f2bf(tv);
                    colsum[j] += tv;
                    colsq[j] = fmaf(tv, tv, colsq[j]);
                }
            }
        }
        __syncthreads();
        const int rr = t >> 1;
        const int hh = (t & 1) * 32;
        u16* outp = (u16*)outv + (size_t)(row0 + rr) * NS + col0 + hh;
#pragma unroll
        for (int k = 0; k < 4; ++k) {
            *(uint4*)(outp + k * 8) = *(const uint4*)(Cs + rr * NB + hh + k * 8);
        }
    } else {
#pragma unroll
        for (int i = 0; i < MI; ++i) {
#pragma unroll
            for (int r = 0; r < 4; ++r) {
                const int grow = row0 + wrow + i * 16 + (lane >> 4) * 4 + r;
                const float rs = rowscale[grow];
#pragma unroll
                for (int j = 0; j < NJ; ++j) {
                    const int gcol = col0 + wcol + j * 16 + lm;
                    const float tv = rs * acc[i][j][r] + bias[gcol];
                    ((float*)outv)[(size_t)grow * NS + gcol] = tv;
                    colsum[j] += tv;
                    colsq[j] = fmaf(tv, tv, colsq[j]);
                }
            }
        }
    }
    const int bb = (blockIdx.y * MB) >> 10;
#pragma unroll
    for (int j = 0; j < NJ; ++j) {
        float s = colsum[j];
        float q = colsq[j];
        s += __shfl_xor(s, 16); s += __shfl_xor(s, 32);
        q += __shfl_xor(q, 16); q += __shfl_xor(q, 32);
        if (lane < 16) {
            const int c = col0 + wcol + j * 16 + lm;
            atomicAdd(&csum[c], s);
            atomicAdd(&csq[c], q);
            if (EPI == 0) atomicAdd(&gsum[bb * NS + c], s);
        }
    }
}

// ---------------- K4: dynamic kernel MLP + fused BN1 stats ----------------
__global__ __launch_bounds__(1024) void dynmlp_kernel(const float* __restrict__ chsum1,
                                                      const float* __restrict__ chsq1,
                                                      const float* __restrict__ gapsum,
                                                      const float* __restrict__ g1,
                                                      const float* __restrict__ be1,
                                                      const float* __restrict__ aw1,
                                                      const float* __restrict__ ab1,
                                                      const float* __restrict__ aw2,
                                                      const float* __restrict__ ab2,
                                                      float* __restrict__ scale1,
                                                      float* __restrict__ shift1,
                                                      float* __restrict__ kw) {
    const int b = blockIdx.x;
    const int t = threadIdx.x;
    const int wave = t >> 6, lane = t & 63;
    __shared__ float g[1024];
    __shared__ float h1[128];
    __shared__ float logits[12];
    {
        const float m = chsum1[t] * (1.0f / (float)M);
        const float var = chsq1[t] * (1.0f / (float)M) - m * m;
        const float rstd = rsqrtf(var + EPS);
        const float sc = rstd * g1[t];
        const float sh = be1[t] - m * sc;
        if (b == 0) { scale1[t] = sc; shift1[t] = sh; }
        g[t] = gapsum[b * C + t] * (1.0f / (float)P) * sc + sh;
    }
    __syncthreads();
#pragma unroll
    for (int k = 0; k < 8; ++k) {
        const int u = wave * 8 + k;
        const float4* wr = (const float4*)(aw1 + (size_t)u * C);
        float s = 0.f;
#pragma unroll
        for (int ch = 0; ch < 4; ++ch) {
            const float4 wv = wr[lane + 64 * ch];
            const float4 sv = *(const float4*)(g + 4 * lane + 256 * ch);
            s += wv.x * sv.x + wv.y * sv.y + wv.z * sv.z + wv.w * sv.w;
        }
#pragma unroll
        for (int off = 1; off < 64; off <<= 1) s += __shfl_xor(s, off);
        if (lane == 0) h1[u] = fmaxf(s + ab1[u], 0.f);
    }
    __syncthreads();
    if (wave < 9) {
        float s = aw2[wave * 128 + lane] * h1[lane]
                + aw2[wave * 128 + 64 + lane] * h1[64 + lane];
#pragma unroll
        for (int off = 1; off < 64; off <<= 1) s += __shfl_xor(s, off);
        if (lane == 0) logits[wave] = s + ab2[wave];
    }
    __syncthreads();
    if (t == 0) {
        float mx = logits[0];
        for (int i = 1; i < 9; ++i) mx = fmaxf(mx, logits[i]);
        float e[9], den = 0.f;
        for (int i = 0; i < 9; ++i) { e[i] = expf(logits[i] - mx); den += e[i]; }
        const float inv = 1.0f / den;
        for (int i = 0; i < 9; ++i) kw[b * 9 + i] = e[i] * inv;
    }
}

// ---------------- K5: dyn depthwise conv v2 — W-split + batched 4-wide loads ----------------
// grid: (4, B*H); blockIdx.x bit0 = w-half, bit1 = channel-half. 2 channels/thread.
__global__ __launch_bounds__(256) void dwconv_kernel(const u16* __restrict__ t1b,
                                                     const float* __restrict__ scale1,
                                                     const float* __restrict__ shift1,
                                                     const float* __restrict__ kw,
                                                     u16* __restrict__ t2b,
                                                     float* __restrict__ chsum2,
                                                     float* __restrict__ chsq2,
                                                     float* __restrict__ bsum2,
                                                     u32* __restrict__ umax2,
                                                     u32* __restrict__ umaxn2) {
    const int bh = blockIdx.y;
    const int b = bh >> 5;
    const int h = bh & 31;
    const int whalf = blockIdx.x & 1;
    const int chalf = blockIdx.x >> 1;
    const int c0 = (chalf * 256 + threadIdx.x) * 2;
    float k[9];
#pragma unroll
    for (int i = 0; i < 9; ++i) k[i] = kw[b * 9 + i];
    const float sc0 = scale1[c0],     sh0 = shift1[c0];
    const float sc1 = scale1[c0 + 1], sh1 = shift1[c0 + 1];
    const u16* base = t1b + (size_t)b * P * C + c0;
    const bool rok[3] = { h > 0, true, h < H - 1 };
    const int w0 = whalf * 16;

    float s0 = 0.f, q0 = 0.f, mx0 = -INFINITY, mn0 = INFINITY;
    float s1 = 0.f, q1 = 0.f, mx1 = -INFINITY, mn1 = INFINITY;
#pragma unroll
    for (int g = 0; g < 4; ++g) {
        const int wb = w0 + g * 4;
        // batched loads: 6 cols x 3 rows, all independent -> one waitcnt per group
        float2 col[6][3];
#pragma unroll
        for (int ci = 0; ci < 6; ++ci) {
            const int ww = wb - 1 + ci;
            const bool wok = (ww >= 0) && (ww < W);
#pragma unroll
            for (int ri = 0; ri < 3; ++ri) {
                if (wok && rok[ri]) {
                    const u32 v = *(const u32*)(base + ((size_t)((h + ri - 1) * W + ww)) * C);
                    col[ci][ri].x = fmaf(bf2f((u16)(v & 0xffff)), sc0, sh0);
                    col[ci][ri].y = fmaf(bf2f((u16)(v >> 16)),    sc1, sh1);
                } else {
                    col[ci][ri].x = 0.f;
                    col[ci][ri].y = 0.f;
                }
            }
        }
#pragma unroll
        for (int o = 0; o < 4; ++o) {
            float a0 = 0.f, a1 = 0.f;
#pragma unroll
            for (int ri = 0; ri < 3; ++ri)
#pragma unroll
                for (int cj = 0; cj < 3; ++cj) {
                    a0 = fmaf(k[ri * 3 + cj], col[o + cj][ri].x, a0);
                    a1 = fmaf(k[ri * 3 + cj], col[o + cj][ri].y, a1);
                }
            const float y0 = gelu_exact(a0);
            const float y1 = gelu_exact(a1);
            *(u32*)(t2b + ((size_t)b * P + h * W + wb + o) * C + c0) =
                ((u32)f2bf(y0)) | ((u32)f2bf(y1) << 16);
            s0 += y0; q0 = fmaf(y0, y0, q0); mx0 = fmaxf(mx0, y0); mn0 = fminf(mn0, y0);
            s1 += y1; q1 = fmaf(y1, y1, q1); mx1 = fmaxf(mx1, y1); mn1 = fminf(mn1, y1);
        }
    }
    // BN2 stat atomics
    atomicAdd(&chsum2[c0], s0);      atomicAdd(&chsum2[c0 + 1], s1);
    atomicAdd(&chsq2[c0], q0);       atomicAdd(&chsq2[c0 + 1], q1);
    atomicAdd(&bsum2[b * C + c0], s0);       atomicAdd(&bsum2[b * C + c0 + 1], s1);
    atomicMax(&umax2[b * C + c0], fkey(mx0));   atomicMax(&umax2[b * C + c0 + 1], fkey(mx1));
    atomicMax(&umaxn2[b * C + c0], fkey(-mn0)); atomicMax(&umaxn2[b * C + c0 + 1], fkey(-mn1));
}

// ---------------- K8: channel attention + O(1) BN2 finalize ----------------
__global__ __launch_bounds__(1024) void chatt_kernel(const float* __restrict__ chsum2,
                                                     const float* __restrict__ chsq2,
                                                     const float* __restrict__ bsum2,
                                                     const u32* __restrict__ umax2,
                                                     const u32* __restrict__ umaxn2,
                                                     const float* __restrict__ g2,
                                                     const float* __restrict__ be2,
                                                     const float* __restrict__ caw1,
                                                     const float* __restrict__ caw2,
                                                     float* __restrict__ scale2,
                                                     float* __restrict__ shift2,
                                                     float* __restrict__ s_att) {
    const int b = blockIdx.x;
    const int t = threadIdx.x;          // channel
    const int wave = t >> 6, lane = t & 63;
    __shared__ float la[1024], lx[1024], ha[64], hm[64];
    {
        const float m = chsum2[t] * (1.0f / (float)M);
        const float var = chsq2[t] * (1.0f / (float)M) - m * m;
        const float rstd = rsqrtf(var + EPS);
        const float sc = rstd * g2[t];
        const float sh = be2[t] - m * sc;
        if (b == 0) { scale2[t] = sc; shift2[t] = sh; }
        la[t] = bsum2[b * C + t] * (1.0f / (float)P) * sc + sh;
        const float mx = fkeyinv(umax2[b * C + t]);
        const float mn = -fkeyinv(umaxn2[b * C + t]);
        lx[t] = (sc >= 0.f ? mx : mn) * sc + sh;
    }
    __syncthreads();
#pragma unroll
    for (int k = 0; k < 8; ++k) {
        const int u = wave * 8 + k;
        const int row = u & 63;
        const float* src = (u < 64) ? la : lx;
        const float4* wr = (const float4*)(caw1 + (size_t)row * C);
        float s = 0.f;
#pragma unroll
        for (int ch = 0; ch < 4; ++ch) {
            const float4 wv = wr[lane + 64 * ch];
            const float4 sv = *(const float4*)(src + 4 * lane + 256 * ch);
            s += wv.x * sv.x + wv.y * sv.y + wv.z * sv.z + wv.w * sv.w;
        }
#pragma unroll
        for (int off = 1; off < 64; off <<= 1) s += __shfl_xor(s, off);
        if (lane == 0) {
            s = fmaxf(s, 0.f);
            if (u < 64) ha[row] = s; else hm[row] = s;
        }
    }
    __syncthreads();
    {
        const float4* w2 = (const float4*)(caw2 + (size_t)t * 64);
        float s = 0.f;
#pragma unroll
        for (int j = 0; j < 16; ++j) {
            const float4 wv = w2[j];
            s += wv.x * (ha[j * 4 + 0] + hm[j * 4 + 0]);
            s += wv.y * (ha[j * 4 + 1] + hm[j * 4 + 1]);
            s += wv.z * (ha[j * 4 + 2] + hm[j * 4 + 2]);
            s += wv.w * (ha[j * 4 + 3] + hm[j * 4 + 3]);
        }
        s_att[b * C + t] = 1.0f / (1.0f + expf(-s));
    }
}

// ---------------- K9: y = s_att*bn2(t2) -> bf16 yb + per-row avg/max ----------------
__global__ __launch_bounds__(256) void yq_kernel(const u16* __restrict__ t2b,
                                                 const float* __restrict__ scale2,
                                                 const float* __restrict__ shift2,
                                                 const float* __restrict__ s_att,
                                                 u16* __restrict__ yb,
                                                 float* __restrict__ avg_o,
                                                 float* __restrict__ max_o) {
    const int row = blockIdx.x;       // b*P + p
    const int b = row >> 10;
    const int t = threadIdx.x;
    const int c0 = t * 4;
    const uint2 vv = *(const uint2*)(t2b + (size_t)row * C + c0);
    const float v0 = bf2f((u16)(vv.x & 0xffff));
    const float v1 = bf2f((u16)(vv.x >> 16));
    const float v2 = bf2f((u16)(vv.y & 0xffff));
    const float v3 = bf2f((u16)(vv.y >> 16));
    const float4 sc = *(const float4*)(scale2 + c0);
    const float4 sh = *(const float4*)(shift2 + c0);
    const float4 sa = *(const float4*)(s_att + (size_t)b * C + c0);
    const float y0 = fmaf(v0, sc.x, sh.x) * sa.x;
    const float y1 = fmaf(v1, sc.y, sh.y) * sa.y;
    const float y2 = fmaf(v2, sc.z, sh.z) * sa.z;
    const float y3 = fmaf(v3, sc.w, sh.w) * sa.w;
    uint2 o;
    o.x = ((u32)f2bf(y0)) | ((u32)f2bf(y1) << 16);
    o.y = ((u32)f2bf(y2)) | ((u32)f2bf(y3) << 16);
    *(uint2*)(yb + (size_t)row * C + c0) = o;
    float s = (y0 + y1) + (y2 + y3);
    float mx = fmaxf(fmaxf(y0, y1), fmaxf(y2, y3));
#pragma unroll
    for (int off = 32; off > 0; off >>= 1) {
        s += __shfl_down(s, off);
        mx = fmaxf(mx, __shfl_down(mx, off));
    }
    __shared__ float ss[4], sm[4];
    const int wave = t >> 6, lane = t & 63;
    if (lane == 0) { ss[wave] = s; sm[wave] = mx; }
    __syncthreads();
    if (t == 0) {
        const float S = ss[0] + ss[1] + ss[2] + ss[3];
        const float Mx = fmaxf(fmaxf(sm[0], sm[1]), fmaxf(sm[2], sm[3]));
        avg_o[row] = S * (1.0f / (float)C);
        max_o[row] = Mx;
    }
}

// ---------------- K10: 7x7 spatial conv + sigmoid (1 pixel/thread) ----------------
__global__ __launch_bounds__(1024) void spconv_kernel(const float* __restrict__ avg_o,
                                                      const float* __restrict__ max_o,
                                                      const float* __restrict__ sw,
                                                      const float* __restrict__ sb,
                                                      float* __restrict__ sp) {
    const int b = blockIdx.x;
    const int t = threadIdx.x;
    __shared__ float pa[P], pm[P], wsh[98];
    pa[t] = avg_o[b * P + t];
    pm[t] = max_o[b * P + t];
    if (t < 98) wsh[t] = sw[t];
    const float sbv = sb[0];
    __syncthreads();
    const int h = t >> 5, w = t & 31;
    float acc = sbv;
#pragma unroll
    for (int i = 0; i < 7; ++i) {
        const int hh = h + i - 3;
        if (hh < 0 || hh >= H) continue;
#pragma unroll
        for (int j = 0; j < 7; ++j) {
            const int ww = w + j - 3;
            if (ww < 0 || ww >= W) continue;
            const int pidx = hh * W + ww;
            acc = fmaf(wsh[i * 7 + j], pa[pidx], acc);
            acc = fmaf(wsh[49 + i * 7 + j], pm[pidx], acc);
        }
    }
    sp[b * P + t] = 1.0f / (1.0f + expf(-acc));
}

// ---------------- K15: final residual add + fused BN3 stats ----------------
__global__ __launch_bounds__(256) void final_kernel(const float* __restrict__ x,
                                                    const float* __restrict__ pre,
                                                    const float* __restrict__ chsum3,
                                                    const float* __restrict__ chsq3,
                                                    const float* __restrict__ g3,
                                                    const float* __restrict__ be3,
                                                    float* __restrict__ out) {
    __shared__ float lsc[256], lsh[256];
    const int t = threadIdx.x;
    {
        const float m = chsum3[t] * (1.0f / (float)M);
        const float var = chsq3[t] * (1.0f / (float)M) - m * m;
        const float rstd = rsqrtf(var + EPS);
        const float sc = rstd * g3[t];
        lsc[t] = sc;
        lsh[t] = be3[t] - m * sc;
    }
    __syncthreads();
    const int i = blockIdx.x * 256 + t;   // float4 index
    const int e = i * 4;
    const int d = e & 255;
    const float4 xv = *(const float4*)(x + e);
    const float4 pv = *(const float4*)(pre + e);
    const float4 sc = *(const float4*)(lsc + d);
    const float4 sh = *(const float4*)(lsh + d);
    float4 o;
    o.x = xv.x + fmaf(pv.x, sc.x, sh.x);
    o.y = xv.y + fmaf(pv.y, sc.y, sh.y);
    o.z = xv.z + fmaf(pv.z, sc.z, sh.z);
    o.w = xv.w + fmaf(pv.w, sc.w, sh.w);
    *(float4*)(out + e) = o;
}

extern "C" void kernel_launch(void* const* d_in, const int* in_sizes, int n_in,
                              void* d_out, int out_size, void* d_ws, size_t ws_size,
                              hipStream_t stream) {
    const float* x    = (const float*)d_in[0];
    const float* w1   = (const float*)d_in[1];
    const float* b1   = (const float*)d_in[2];
    const float* g1   = (const float*)d_in[3];
    const float* be1  = (const float*)d_in[4];
    const float* aw1  = (const float*)d_in[5];
    const float* ab1  = (const float*)d_in[6];
    const float* aw2  = (const float*)d_in[7];
    const float* ab2  = (const float*)d_in[8];
    const float* g2   = (const float*)d_in[9];
    const float* be2  = (const float*)d_in[10];
    const float* caw1 = (const float*)d_in[11];
    const float* caw2 = (const float*)d_in[12];
    const float* pw   = (const float*)d_in[13];
    const float* pb   = (const float*)d_in[14];
    const float* g3   = (const float*)d_in[15];
    const float* be3  = (const float*)d_in[16];
    const float* sw   = (const float*)d_in[17];
    const float* sb   = (const float*)d_in[18];
    float* out = (float*)d_out;
    float* ws = (float*)d_ws;

    float* chsum1  = ws + WS_CHSUM1;
    float* chsq1   = ws + WS_CHSQ1;
    float* gapsum  = ws + WS_GAPSUM;
    float* chsum3  = ws + WS_CHSUM3;
    float* chsq3   = ws + WS_CHSQ3;
    float* chsum2  = ws + WS_CHSUM2;
    float* chsq2   = ws + WS_CHSQ2;
    float* bsum2   = ws + WS_BSUM2;
    u32*   umax2   = (u32*)(ws + WS_UMAX2);
    u32*   umaxn2  = (u32*)(ws + WS_UMAXN2);
    float* scale1  = ws + WS_SCALE1;
    float* shift1  = ws + WS_SHIFT1;
    float* kw      = ws + WS_KW;
    float* scale2  = ws + WS_SCALE2;
    float* shift2  = ws + WS_SHIFT2;
    float* s_att   = ws + WS_SATT;
    float* avg_o   = ws + WS_AVGO;
    float* max_o   = ws + WS_MAXO;
    float* sp      = ws + WS_SP;
    float* pre     = ws + WS_PRE;
    u16* t1b = (u16*)(ws + WS_T1B);
    u16* t2b = (u16*)(ws + WS_T2B);
    u16* xb  = (u16*)(ws + WS_XB);
    u16* w1b = (u16*)(ws + WS_W1B);
    u16* pwb = (u16*)(ws + WS_PWB);
    u16* yb  = (u16*)(ws + WS_YB);

    // K0: zero accumulators + all casts in one launch
    cvt_all_kernel<<<dim3(2560), 256, 0, stream>>>(x, w1, pw, xb, w1b, pwb, ws);
    // K1: expand GEMM (bf16 MFMA, 128x64 tile, 1024 blocks) + bias + GELU -> bf16 t1
    mfma_gemm_kernel<256, 0, C, 128, 64><<<dim3(C / 64, M / 128), 256, 16384, stream>>>(
        xb, w1b, b1, nullptr, t1b, chsum1, chsq1, gapsum);
    // K4: BN1 stats + gap + dynamic kernel weights (fused)
    dynmlp_kernel<<<dim3(B), 1024, 0, stream>>>(chsum1, chsq1, gapsum, g1, be1,
                                                aw1, ab1, aw2, ab2, scale1, shift1, kw);
    // K5: depthwise conv v2 (1024 blocks, batched loads) + GELU -> bf16 t2, BN2 atomics
    dwconv_kernel<<<dim3(4, B * H), 256, 0, stream>>>(t1b, scale1, shift1, kw, t2b,
                                                      chsum2, chsq2, bsum2, umax2, umaxn2);
    // K8: BN2 finalize (O(1)/thread) + channel attention
    chatt_kernel<<<dim3(B), 1024, 0, stream>>>(chsum2, chsq2, bsum2, umax2, umaxn2,
                                               g2, be2, caw1, caw2, scale2, shift2, s_att);
    // K9: y quantize + spatial stats
    yq_kernel<<<dim3(M), 256, 0, stream>>>(t2b, scale2, shift2, s_att, yb, avg_o, max_o);
    // K10: 7x7 conv + sigmoid
    spconv_kernel<<<dim3(B), 1024, 0, stream>>>(avg_o, max_o, sw, sb, sp);
    // K12: project GEMM (bf16 MFMA, 64x64 tile, 512 blocks) + sp/bias epilogue
    mfma_gemm_kernel<1024, 1, D, 64, 64><<<dim3(D / 64, M / 64), 256, 8192, stream>>>(
        yb, pwb, pb, sp, pre, chsum3, chsq3, nullptr);
    // K15: BN3 stats + final residual add (fused)
    final_kernel<<<dim3((M * D / 4) / 256), 256, 0, stream>>>(x, pre, chsum3, chsq3, g3, be3, out);
}

// Round 11
// 212.775 us; speedup vs baseline: 1.0853x; 1.0853x over previous
//
#include <hip/hip_runtime.h>
#include <math.h>

// Problem constants
constexpr int B = 8;
constexpr int D = 256;     // model dim
constexpr int C = 1024;    // expanded channels
constexpr int H = 32, W = 32;
constexpr int P = H * W;            // 1024 spatial positions
constexpr int M = B * P;            // 8192 rows
constexpr float EPS = 1e-5f;

typedef unsigned short u16;
typedef unsigned int u32;
typedef __attribute__((ext_vector_type(8))) short short8;
typedef __attribute__((ext_vector_type(4))) float floatx4;

// ---------------- workspace layout (in floats) ----------------
// zero-initialized accumulator region (zeroed by cvt kernel)
constexpr size_t WS_CHSUM1 = 0;                  // 1024
constexpr size_t WS_CHSQ1  = 1024;               // 1024
constexpr size_t WS_GAPSUM = 2048;               // 8192
constexpr size_t WS_CHSUM3 = 10240;              // 256
constexpr size_t WS_CHSQ3  = 10496;              // 256
constexpr size_t WS_CHSUM2 = 10752;              // 1024
constexpr size_t WS_CHSQ2  = 11776;              // 1024
constexpr size_t WS_BSUM2  = 12800;              // 8192
constexpr size_t WS_UMAX2  = 20992;              // 8192 (u32 keys)
constexpr size_t WS_UMAXN2 = 29184;              // 8192 (u32 keys of -min)
constexpr size_t WS_ACC_COUNT = 37376;
// non-zeroed
constexpr size_t WS_SCALE1 = 37376;              // 1024
constexpr size_t WS_SHIFT1 = 38400;              // 1024
constexpr size_t WS_KW     = 39424;              // 256 (72 used)
constexpr size_t WS_SCALE2 = 39680;              // 1024
constexpr size_t WS_SHIFT2 = 40704;              // 1024
constexpr size_t WS_SATT   = 41728;              // 8192
constexpr size_t WS_AVGO   = 49920;              // 8192
constexpr size_t WS_MAXO   = 58112;              // 8192
constexpr size_t WS_SP     = 66304;              // 8192
constexpr size_t WS_PRE    = 74496;              // 2097152
constexpr size_t WS_T1B    = 2171648;            // bf16 t1 (4194304 floats)
constexpr size_t WS_T2B    = 6365952;            // bf16 t2
constexpr size_t WS_XB     = 10560256;           // bf16 x
constexpr size_t WS_W1B    = 11608832;
constexpr size_t WS_PWB    = 11739904;
constexpr size_t WS_YB     = 11870976;           // bf16 y
// total = 16065280 floats = 64.3 MB

__device__ __forceinline__ float gelu_exact(float v) {
    return 0.5f * v * (1.0f + erff(v * 0.70710678118654752440f));
}

__device__ __forceinline__ u16 f2bf(float f) {
    u32 u = __float_as_uint(f);
    u += 0x7fff + ((u >> 16) & 1);   // round-to-nearest-even
    return (u16)(u >> 16);
}

__device__ __forceinline__ float bf2f(u16 v) {
    return __uint_as_float(((u32)v) << 16);
}

// order-preserving float->u32 key: unsigned compare order == float order
__device__ __forceinline__ u32 fkey(float f) {
    u32 u = __float_as_uint(f);
    return (u & 0x80000000u) ? ~u : (u | 0x80000000u);
}
__device__ __forceinline__ float fkeyinv(u32 k) {
    return __uint_as_float((k & 0x80000000u) ? (k ^ 0x80000000u) : ~k);
}

// ---------------- K0: zero accumulators + cast fp32 -> bf16 for x, w1, pw ----------------
__global__ __launch_bounds__(256) void cvt_all_kernel(const float* __restrict__ x,
                                                      const float* __restrict__ w1,
                                                      const float* __restrict__ pw,
                                                      u16* __restrict__ xb,
                                                      u16* __restrict__ w1b,
                                                      u16* __restrict__ pwb,
                                                      float* __restrict__ acc_zero) {
    const int i = blockIdx.x * 256 + threadIdx.x;
    if (i < (int)WS_ACC_COUNT) acc_zero[i] = 0.f;   // 0x0 == fkey floor for max-keys too
    const float* src;
    u16* dst;
    int off;
    if (i < 524288)      { src = x;  dst = xb;  off = i; }
    else if (i < 589824) { src = w1; dst = w1b; off = i - 524288; }
    else                 { src = pw; dst = pwb; off = i - 589824; }
    const float4 v = *(const float4*)(src + (size_t)off * 4);
    uint2 o;
    o.x = ((u32)f2bf(v.x)) | ((u32)f2bf(v.y) << 16);
    o.y = ((u32)f2bf(v.z)) | ((u32)f2bf(v.w) << 16);
    *(uint2*)(dst + (size_t)off * 4) = o;
}

// ---------------- MFMA bf16 GEMM + fused epilogue + fused column stats (R7-proven) ----------------
template<int KD, int EPI, int NS, int MB, int NB>
__global__ __launch_bounds__(256) void mfma_gemm_kernel(
    const u16* __restrict__ A,
    const u16* __restrict__ Bw,
    const float* __restrict__ bias,
    const float* __restrict__ rowscale,
    void* __restrict__ outv,
    float* __restrict__ csum,
    float* __restrict__ csq,
    float* __restrict__ gsum)
{
    constexpr int MI = MB / 32;
    constexpr int NJ = NB / 32;
    extern __shared__ u16 smem[];
    u16* As = smem;
    u16* Bs = smem + MB * 32;
    const int t = threadIdx.x;
    const int lane = t & 63;
    const int row0 = blockIdx.y * MB;
    const int col0 = blockIdx.x * NB;
    const int wv = t >> 6;
    const int wrow = (wv >> 1) * (MB / 2);
    const int wcol = (wv & 1) * (NB / 2);
    const int lm = lane & 15;
    const int lk8 = (lane >> 4) * 8;
    const int srow = t >> 2;
    const int scol = (t & 3) * 8;
    const u16* gA0 = A + (size_t)(row0 + srow) * KD + scol;
    const u16* gA1 = A + (size_t)(row0 + 64 + srow) * KD + scol;
    const u16* gB0 = Bw + (size_t)(col0 + srow) * KD + scol;
    const floatx4 zero = {0.f, 0.f, 0.f, 0.f};
    floatx4 acc[MI][NJ];
#pragma unroll
    for (int i = 0; i < MI; ++i)
#pragma unroll
        for (int j = 0; j < NJ; ++j) acc[i][j] = zero;
    for (int k0 = 0; k0 < KD; k0 += 32) {
        __builtin_amdgcn_global_load_lds(
            (const __attribute__((address_space(1))) void*)(gA0 + k0),
            (__attribute__((address_space(3))) void*)(As + t * 8), 16, 0, 0);
        if (MB == 128)
            __builtin_amdgcn_global_load_lds(
                (const __attribute__((address_space(1))) void*)(gA1 + k0),
                (__attribute__((address_space(3))) void*)(As + 2048 + t * 8), 16, 0, 0);
        __builtin_amdgcn_global_load_lds(
            (const __attribute__((address_space(1))) void*)(gB0 + k0),
            (__attribute__((address_space(3))) void*)(Bs + t * 8), 16, 0, 0);
        __syncthreads();
        short8 af[MI], bf[NJ];
#pragma unroll
        for (int i = 0; i < MI; ++i)
            af[i] = *(const short8*)(As + (wrow + i * 16 + lm) * 32 + lk8);
#pragma unroll
        for (int j = 0; j < NJ; ++j)
            bf[j] = *(const short8*)(Bs + (wcol + j * 16 + lm) * 32 + lk8);
#pragma unroll
        for (int i = 0; i < MI; ++i)
#pragma unroll
            for (int j = 0; j < NJ; ++j)
                acc[i][j] = __builtin_amdgcn_mfma_f32_16x16x32_bf16(af[i], bf[j], acc[i][j], 0, 0, 0);
        __syncthreads();
    }
    float colsum[NJ], colsq[NJ];
#pragma unroll
    for (int j = 0; j < NJ; ++j) { colsum[j] = 0.f; colsq[j] = 0.f; }
    if (EPI == 0) {
        u16* Cs = smem;
#pragma unroll
        for (int i = 0; i < MI; ++i) {
#pragma unroll
            for (int r = 0; r < 4; ++r) {
                const int lrow = wrow + i * 16 + (lane >> 4) * 4 + r;
#pragma unroll
                for (int j = 0; j < NJ; ++j) {
                    const int lcol = wcol + j * 16 + lm;
                    const float tv = gelu_exact(acc[i][j][r] + bias[col0 + lcol]);
                    Cs[lrow * NB + lcol] = f2bf(tv);
                    colsum[j] += tv;
                    colsq[j] = fmaf(tv, tv, colsq[j]);
                }
            }
        }
        __syncthreads();
        const int rr = t >> 1;
        const int hh = (t & 1) * 32;
        u16* outp = (u16*)outv + (size_t)(row0 + rr) * NS + col0 + hh;
#pragma unroll
        for (int k = 0; k < 4; ++k) {
            *(uint4*)(outp + k * 8) = *(const uint4*)(Cs + rr * NB + hh + k * 8);
        }
    } else {
#pragma unroll
        for (int i = 0; i < MI; ++i) {
#pragma unroll
            for (int r = 0; r < 4; ++r) {
                const int grow = row0 + wrow + i * 16 + (lane >> 4) * 4 + r;
                const float rs = rowscale[grow];
#pragma unroll
                for (int j = 0; j < NJ; ++j) {
                    const int gcol = col0 + wcol + j * 16 + lm;
                    const float tv = rs * acc[i][j][r] + bias[gcol];
                    ((float*)outv)[(size_t)grow * NS + gcol] = tv;
                    colsum[j] += tv;
                    colsq[j] = fmaf(tv, tv, colsq[j]);
                }
            }
        }
    }
    const int bb = (blockIdx.y * MB) >> 10;
#pragma unroll
    for (int j = 0; j < NJ; ++j) {
        float s = colsum[j];
        float q = colsq[j];
        s += __shfl_xor(s, 16); s += __shfl_xor(s, 32);
        q += __shfl_xor(q, 16); q += __shfl_xor(q, 32);
        if (lane < 16) {
            const int c = col0 + wcol + j * 16 + lm;
            atomicAdd(&csum[c], s);
            atomicAdd(&csq[c], q);
            if (EPI == 0) atomicAdd(&gsum[bb * NS + c], s);
        }
    }
}

// ---------------- K4: dynamic kernel MLP + fused BN1 stats ----------------
__global__ __launch_bounds__(1024) void dynmlp_kernel(const float* __restrict__ chsum1,
                                                      const float* __restrict__ chsq1,
                                                      const float* __restrict__ gapsum,
                                                      const float* __restrict__ g1,
                                                      const float* __restrict__ be1,
                                                      const float* __restrict__ aw1,
                                                      const float* __restrict__ ab1,
                                                      const float* __restrict__ aw2,
                                                      const float* __restrict__ ab2,
                                                      float* __restrict__ scale1,
                                                      float* __restrict__ shift1,
                                                      float* __restrict__ kw) {
    const int b = blockIdx.x;
    const int t = threadIdx.x;
    const int wave = t >> 6, lane = t & 63;
    __shared__ float g[1024];
    __shared__ float h1[128];
    __shared__ float logits[12];
    {
        const float m = chsum1[t] * (1.0f / (float)M);
        const float var = chsq1[t] * (1.0f / (float)M) - m * m;
        const float rstd = rsqrtf(var + EPS);
        const float sc = rstd * g1[t];
        const float sh = be1[t] - m * sc;
        if (b == 0) { scale1[t] = sc; shift1[t] = sh; }
        g[t] = gapsum[b * C + t] * (1.0f / (float)P) * sc + sh;
    }
    __syncthreads();
#pragma unroll
    for (int k = 0; k < 8; ++k) {
        const int u = wave * 8 + k;
        const float4* wr = (const float4*)(aw1 + (size_t)u * C);
        float s = 0.f;
#pragma unroll
        for (int ch = 0; ch < 4; ++ch) {
            const float4 wv = wr[lane + 64 * ch];
            const float4 sv = *(const float4*)(g + 4 * lane + 256 * ch);
            s += wv.x * sv.x + wv.y * sv.y + wv.z * sv.z + wv.w * sv.w;
        }
#pragma unroll
        for (int off = 1; off < 64; off <<= 1) s += __shfl_xor(s, off);
        if (lane == 0) h1[u] = fmaxf(s + ab1[u], 0.f);
    }
    __syncthreads();
    if (wave < 9) {
        float s = aw2[wave * 128 + lane] * h1[lane]
                + aw2[wave * 128 + 64 + lane] * h1[64 + lane];
#pragma unroll
        for (int off = 1; off < 64; off <<= 1) s += __shfl_xor(s, off);
        if (lane == 0) logits[wave] = s + ab2[wave];
    }
    __syncthreads();
    if (t == 0) {
        float mx = logits[0];
        for (int i = 1; i < 9; ++i) mx = fmaxf(mx, logits[i]);
        float e[9], den = 0.f;
        for (int i = 0; i < 9; ++i) { e[i] = expf(logits[i] - mx); den += e[i]; }
        const float inv = 1.0f / den;
        for (int i = 0; i < 9; ++i) kw[b * 9 + i] = e[i] * inv;
    }
}

// ---------------- K5: dyn depthwise conv v3 — LDS-staged rows, zero global in inner loop ----------------
// grid: (4, B*H); blockIdx.x = channel quarter (256 ch), blockIdx.y = b*32+h. 1 channel/thread.
__global__ __launch_bounds__(256) void dwconv_kernel(const u16* __restrict__ t1b,
                                                     const float* __restrict__ scale1,
                                                     const float* __restrict__ shift1,
                                                     const float* __restrict__ kw,
                                                     u16* __restrict__ t2b,
                                                     float* __restrict__ chsum2,
                                                     float* __restrict__ chsq2,
                                                     float* __restrict__ bsum2,
                                                     u32* __restrict__ umax2,
                                                     u32* __restrict__ umaxn2) {
    __shared__ u16 rows[3 * 32 * 256];   // 48 KB: [r][w][ch]
    const int bh = blockIdx.y;
    const int b = bh >> 5;
    const int h = bh & 31;
    const int cq = blockIdx.x;
    const int t = threadIdx.x;

    // stage 3 rows (h-1, h, h+1) x 32 w x 256 ch; OOB rows left zero (predicated in compute anyway)
    const u16* gbase = t1b + (size_t)b * P * C + cq * 256;
#pragma unroll
    for (int i = 0; i < 12; ++i) {
        const int lin = i * 256 + t;         // 16B-unit index, 0..3071
        const int chunk = lin >> 5;          // (r*32 + w), 0..95
        const int r = chunk >> 5;            // 0..2
        const int w = chunk & 31;
        const int off8 = (lin & 31) * 8;     // u16 offset within 512B chunk
        const int hr = h + r - 1;
        uint4 v = {0u, 0u, 0u, 0u};
        if (hr >= 0 && hr < H)
            v = *(const uint4*)(gbase + (size_t)(hr * W + w) * C + off8);
        *(uint4*)(&rows[chunk * 256 + off8]) = v;
    }
    __syncthreads();

    const int c = t;                 // channel within quarter
    const int gc = cq * 256 + c;
    float k[9];
#pragma unroll
    for (int i = 0; i < 9; ++i) k[i] = kw[b * 9 + i];
    const float sc = scale1[gc];
    const float sh = shift1[gc];
    const bool rok[3] = { h > 0, true, h < H - 1 };

    float s = 0.f, q = 0.f, mx = -INFINITY, mn = INFINITY;
    for (int w = 0; w < W; ++w) {
        float acc = 0.f;
#pragma unroll
        for (int ri = 0; ri < 3; ++ri) {
            if (!rok[ri]) continue;                    // wave-uniform branch
            const u16* rp = rows + (ri * 32) * 256 + c;
            if (w > 0)
                acc = fmaf(k[ri * 3 + 0], fmaf(bf2f(rp[(w - 1) * 256]), sc, sh), acc);
            acc = fmaf(k[ri * 3 + 1], fmaf(bf2f(rp[w * 256]), sc, sh), acc);
            if (w < W - 1)
                acc = fmaf(k[ri * 3 + 2], fmaf(bf2f(rp[(w + 1) * 256]), sc, sh), acc);
        }
        const float y = gelu_exact(acc);
        t2b[((size_t)b * P + h * W + w) * C + gc] = f2bf(y);
        s += y;
        q = fmaf(y, y, q);
        mx = fmaxf(mx, y);
        mn = fminf(mn, y);
    }
    // BN2 stat atomics
    atomicAdd(&chsum2[gc], s);
    atomicAdd(&chsq2[gc], q);
    atomicAdd(&bsum2[b * C + gc], s);
    atomicMax(&umax2[b * C + gc], fkey(mx));
    atomicMax(&umaxn2[b * C + gc], fkey(-mn));
}

// ---------------- K8: channel attention + O(1) BN2 finalize ----------------
__global__ __launch_bounds__(1024) void chatt_kernel(const float* __restrict__ chsum2,
                                                     const float* __restrict__ chsq2,
                                                     const float* __restrict__ bsum2,
                                                     const u32* __restrict__ umax2,
                                                     const u32* __restrict__ umaxn2,
                                                     const float* __restrict__ g2,
                                                     const float* __restrict__ be2,
                                                     const float* __restrict__ caw1,
                                                     const float* __restrict__ caw2,
                                                     float* __restrict__ scale2,
                                                     float* __restrict__ shift2,
                                                     float* __restrict__ s_att) {
    const int b = blockIdx.x;
    const int t = threadIdx.x;          // channel
    const int wave = t >> 6, lane = t & 63;
    __shared__ float la[1024], lx[1024], ha[64], hm[64];
    {
        const float m = chsum2[t] * (1.0f / (float)M);
        const float var = chsq2[t] * (1.0f / (float)M) - m * m;
        const float rstd = rsqrtf(var + EPS);
        const float sc = rstd * g2[t];
        const float sh = be2[t] - m * sc;
        if (b == 0) { scale2[t] = sc; shift2[t] = sh; }
        la[t] = bsum2[b * C + t] * (1.0f / (float)P) * sc + sh;
        const float mx = fkeyinv(umax2[b * C + t]);
        const float mn = -fkeyinv(umaxn2[b * C + t]);
        lx[t] = (sc >= 0.f ? mx : mn) * sc + sh;
    }
    __syncthreads();
#pragma unroll
    for (int k = 0; k < 8; ++k) {
        const int u = wave * 8 + k;
        const int row = u & 63;
        const float* src = (u < 64) ? la : lx;
        const float4* wr = (const float4*)(caw1 + (size_t)row * C);
        float s = 0.f;
#pragma unroll
        for (int ch = 0; ch < 4; ++ch) {
            const float4 wv = wr[lane + 64 * ch];
            const float4 sv = *(const float4*)(src + 4 * lane + 256 * ch);
            s += wv.x * sv.x + wv.y * sv.y + wv.z * sv.z + wv.w * sv.w;
        }
#pragma unroll
        for (int off = 1; off < 64; off <<= 1) s += __shfl_xor(s, off);
        if (lane == 0) {
            s = fmaxf(s, 0.f);
            if (u < 64) ha[row] = s; else hm[row] = s;
        }
    }
    __syncthreads();
    {
        const float4* w2 = (const float4*)(caw2 + (size_t)t * 64);
        float s = 0.f;
#pragma unroll
        for (int j = 0; j < 16; ++j) {
            const float4 wv = w2[j];
            s += wv.x * (ha[j * 4 + 0] + hm[j * 4 + 0]);
            s += wv.y * (ha[j * 4 + 1] + hm[j * 4 + 1]);
            s += wv.z * (ha[j * 4 + 2] + hm[j * 4 + 2]);
            s += wv.w * (ha[j * 4 + 3] + hm[j * 4 + 3]);
        }
        s_att[b * C + t] = 1.0f / (1.0f + expf(-s));
    }
}

// ---------------- K9: y = s_att*bn2(t2) -> bf16 yb + per-row avg/max ----------------
__global__ __launch_bounds__(256) void yq_kernel(const u16* __restrict__ t2b,
                                                 const float* __restrict__ scale2,
                                                 const float* __restrict__ shift2,
                                                 const float* __restrict__ s_att,
                                                 u16* __restrict__ yb,
                                                 float* __restrict__ avg_o,
                                                 float* __restrict__ max_o) {
    const int row = blockIdx.x;       // b*P + p
    const int b = row >> 10;
    const int t = threadIdx.x;
    const int c0 = t * 4;
    const uint2 vv = *(const uint2*)(t2b + (size_t)row * C + c0);
    const float v0 = bf2f((u16)(vv.x & 0xffff));
    const float v1 = bf2f((u16)(vv.x >> 16));
    const float v2 = bf2f((u16)(vv.y & 0xffff));
    const float v3 = bf2f((u16)(vv.y >> 16));
    const float4 sc = *(const float4*)(scale2 + c0);
    const float4 sh = *(const float4*)(shift2 + c0);
    const float4 sa = *(const float4*)(s_att + (size_t)b * C + c0);
    const float y0 = fmaf(v0, sc.x, sh.x) * sa.x;
    const float y1 = fmaf(v1, sc.y, sh.y) * sa.y;
    const float y2 = fmaf(v2, sc.z, sh.z) * sa.z;
    const float y3 = fmaf(v3, sc.w, sh.w) * sa.w;
    uint2 o;
    o.x = ((u32)f2bf(y0)) | ((u32)f2bf(y1) << 16);
    o.y = ((u32)f2bf(y2)) | ((u32)f2bf(y3) << 16);
    *(uint2*)(yb + (size_t)row * C + c0) = o;
    float s = (y0 + y1) + (y2 + y3);
    float mx = fmaxf(fmaxf(y0, y1), fmaxf(y2, y3));
#pragma unroll
    for (int off = 32; off > 0; off >>= 1) {
        s += __shfl_down(s, off);
        mx = fmaxf(mx, __shfl_down(mx, off));
    }
    __shared__ float ss[4], sm[4];
    const int wave = t >> 6, lane = t & 63;
    if (lane == 0) { ss[wave] = s; sm[wave] = mx; }
    __syncthreads();
    if (t == 0) {
        const float S = ss[0] + ss[1] + ss[2] + ss[3];
        const float Mx = fmaxf(fmaxf(sm[0], sm[1]), fmaxf(sm[2], sm[3]));
        avg_o[row] = S * (1.0f / (float)C);
        max_o[row] = Mx;
    }
}

// ---------------- K10: 7x7 spatial conv + sigmoid (1 pixel/thread) ----------------
__global__ __launch_bounds__(1024) void spconv_kernel(const float* __restrict__ avg_o,
                                                      const float* __restrict__ max_o,
                                                      const float* __restrict__ sw,
                                                      const float* __restrict__ sb,
                                                      float* __restrict__ sp) {
    const int b = blockIdx.x;
    const int t = threadIdx.x;
    __shared__ float pa[P], pm[P], wsh[98];
    pa[t] = avg_o[b * P + t];
    pm[t] = max_o[b * P + t];
    if (t < 98) wsh[t] = sw[t];
    const float sbv = sb[0];
    __syncthreads();
    const int h = t >> 5, w = t & 31;
    float acc = sbv;
#pragma unroll
    for (int i = 0; i < 7; ++i) {
        const int hh = h + i - 3;
        if (hh < 0 || hh >= H) continue;
#pragma unroll
        for (int j = 0; j < 7; ++j) {
            const int ww = w + j - 3;
            if (ww < 0 || ww >= W) continue;
            const int pidx = hh * W + ww;
            acc = fmaf(wsh[i * 7 + j], pa[pidx], acc);
            acc = fmaf(wsh[49 + i * 7 + j], pm[pidx], acc);
        }
    }
    sp[b * P + t] = 1.0f / (1.0f + expf(-acc));
}

// ---------------- K15: final residual add + fused BN3 stats ----------------
__global__ __launch_bounds__(256) void final_kernel(const float* __restrict__ x,
                                                    const float* __restrict__ pre,
                                                    const float* __restrict__ chsum3,
                                                    const float* __restrict__ chsq3,
                                                    const float* __restrict__ g3,
                                                    const float* __restrict__ be3,
                                                    float* __restrict__ out) {
    __shared__ float lsc[256], lsh[256];
    const int t = threadIdx.x;
    {
        const float m = chsum3[t] * (1.0f / (float)M);
        const float var = chsq3[t] * (1.0f / (float)M) - m * m;
        const float rstd = rsqrtf(var + EPS);
        const float sc = rstd * g3[t];
        lsc[t] = sc;
        lsh[t] = be3[t] - m * sc;
    }
    __syncthreads();
    const int i = blockIdx.x * 256 + t;   // float4 index
    const int e = i * 4;
    const int d = e & 255;
    const float4 xv = *(const float4*)(x + e);
    const float4 pv = *(const float4*)(pre + e);
    const float4 sc = *(const float4*)(lsc + d);
    const float4 sh = *(const float4*)(lsh + d);
    float4 o;
    o.x = xv.x + fmaf(pv.x, sc.x, sh.x);
    o.y = xv.y + fmaf(pv.y, sc.y, sh.y);
    o.z = xv.z + fmaf(pv.z, sc.z, sh.z);
    o.w = xv.w + fmaf(pv.w, sc.w, sh.w);
    *(float4*)(out + e) = o;
}

extern "C" void kernel_launch(void* const* d_in, const int* in_sizes, int n_in,
                              void* d_out, int out_size, void* d_ws, size_t ws_size,
                              hipStream_t stream) {
    const float* x    = (const float*)d_in[0];
    const float* w1   = (const float*)d_in[1];
    const float* b1   = (const float*)d_in[2];
    const float* g1   = (const float*)d_in[3];
    const float* be1  = (const float*)d_in[4];
    const float* aw1  = (const float*)d_in[5];
    const float* ab1  = (const float*)d_in[6];
    const float* aw2  = (const float*)d_in[7];
    const float* ab2  = (const float*)d_in[8];
    const float* g2   = (const float*)d_in[9];
    const float* be2  = (const float*)d_in[10];
    const float* caw1 = (const float*)d_in[11];
    const float* caw2 = (const float*)d_in[12];
    const float* pw   = (const float*)d_in[13];
    const float* pb   = (const float*)d_in[14];
    const float* g3   = (const float*)d_in[15];
    const float* be3  = (const float*)d_in[16];
    const float* sw   = (const float*)d_in[17];
    const float* sb   = (const float*)d_in[18];
    float* out = (float*)d_out;
    float* ws = (float*)d_ws;

    float* chsum1  = ws + WS_CHSUM1;
    float* chsq1   = ws + WS_CHSQ1;
    float* gapsum  = ws + WS_GAPSUM;
    float* chsum3  = ws + WS_CHSUM3;
    float* chsq3   = ws + WS_CHSQ3;
    float* chsum2  = ws + WS_CHSUM2;
    float* chsq2   = ws + WS_CHSQ2;
    float* bsum2   = ws + WS_BSUM2;
    u32*   umax2   = (u32*)(ws + WS_UMAX2);
    u32*   umaxn2  = (u32*)(ws + WS_UMAXN2);
    float* scale1  = ws + WS_SCALE1;
    float* shift1  = ws + WS_SHIFT1;
    float* kw      = ws + WS_KW;
    float* scale2  = ws + WS_SCALE2;
    float* shift2  = ws + WS_SHIFT2;
    float* s_att   = ws + WS_SATT;
    float* avg_o   = ws + WS_AVGO;
    float* max_o   = ws + WS_MAXO;
    float* sp      = ws + WS_SP;
    float* pre     = ws + WS_PRE;
    u16* t1b = (u16*)(ws + WS_T1B);
    u16* t2b = (u16*)(ws + WS_T2B);
    u16* xb  = (u16*)(ws + WS_XB);
    u16* w1b = (u16*)(ws + WS_W1B);
    u16* pwb = (u16*)(ws + WS_PWB);
    u16* yb  = (u16*)(ws + WS_YB);

    // K0: zero accumulators + all casts in one launch
    cvt_all_kernel<<<dim3(2560), 256, 0, stream>>>(x, w1, pw, xb, w1b, pwb, ws);
    // K1: expand GEMM (bf16 MFMA, 128x64 tile, 1024 blocks) + bias + GELU -> bf16 t1
    mfma_gemm_kernel<256, 0, C, 128, 64><<<dim3(C / 64, M / 128), 256, 16384, stream>>>(
        xb, w1b, b1, nullptr, t1b, chsum1, chsq1, gapsum);
    // K4: BN1 stats + gap + dynamic kernel weights (fused)
    dynmlp_kernel<<<dim3(B), 1024, 0, stream>>>(chsum1, chsq1, gapsum, g1, be1,
                                                aw1, ab1, aw2, ab2, scale1, shift1, kw);
    // K5: depthwise conv v3 (LDS-staged rows, 1024 blocks) + GELU -> bf16 t2, BN2 atomics
    dwconv_kernel<<<dim3(4, B * H), 256, 0, stream>>>(t1b, scale1, shift1, kw, t2b,
                                                      chsum2, chsq2, bsum2, umax2, umaxn2);
    // K8: BN2 finalize (O(1)/thread) + channel attention
    chatt_kernel<<<dim3(B), 1024, 0, stream>>>(chsum2, chsq2, bsum2, umax2, umaxn2,
                                               g2, be2, caw1, caw2, scale2, shift2, s_att);
    // K9: y quantize + spatial stats
    yq_kernel<<<dim3(M), 256, 0, stream>>>(t2b, scale2, shift2, s_att, yb, avg_o, max_o);
    // K10: 7x7 conv + sigmoid
    spconv_kernel<<<dim3(B), 1024, 0, stream>>>(avg_o, max_o, sw, sb, sp);
    // K12: project GEMM (bf16 MFMA, 64x64 tile, 512 blocks) + sp/bias epilogue
    mfma_gemm_kernel<1024, 1, D, 64, 64><<<dim3(D / 64, M / 64), 256, 8192, stream>>>(
        yb, pwb, pb, sp, pre, chsum3, chsq3, nullptr);
    // K15: BN3 stats + final residual add (fused)
    final_kernel<<<dim3((M * D / 4) / 256), 256, 0, stream>>>(x, pre, chsum3, chsq3, g3, be3, out);
}

// Round 12
// 211.739 us; speedup vs baseline: 1.0906x; 1.0049x over previous
//
#include <hip/hip_runtime.h>
#include <math.h>

// Problem constants
constexpr int B = 8;
constexpr int D = 256;     // model dim
constexpr int C = 1024;    // expanded channels
constexpr int H = 32, W = 32;
constexpr int P = H * W;            // 1024 spatial positions
constexpr int M = B * P;            // 8192 rows
constexpr float EPS = 1e-5f;

typedef unsigned short u16;
typedef unsigned int u32;
typedef __attribute__((ext_vector_type(8))) short short8;
typedef __attribute__((ext_vector_type(4))) float floatx4;

// ---------------- workspace layout (in floats) ----------------
// zero-initialized accumulator region (zeroed by cvt kernel)
constexpr size_t WS_CHSUM1 = 0;                  // 1024
constexpr size_t WS_CHSQ1  = 1024;               // 1024
constexpr size_t WS_GAPSUM = 2048;               // 8192
constexpr size_t WS_CHSUM3 = 10240;              // 256
constexpr size_t WS_CHSQ3  = 10496;              // 256
constexpr size_t WS_CHSUM2 = 10752;              // 1024
constexpr size_t WS_CHSQ2  = 11776;              // 1024
constexpr size_t WS_BSUM2  = 12800;              // 8192
constexpr size_t WS_UMAX2  = 20992;              // 8192 (u32 keys)
constexpr size_t WS_UMAXN2 = 29184;              // 8192 (u32 keys of -min)
constexpr size_t WS_ACC_COUNT = 37376;
// non-zeroed
constexpr size_t WS_SCALE1 = 37376;              // 1024
constexpr size_t WS_SHIFT1 = 38400;              // 1024
constexpr size_t WS_KW     = 39424;              // 256 (72 used)
constexpr size_t WS_SCALE2 = 39680;              // 1024
constexpr size_t WS_SHIFT2 = 40704;              // 1024
constexpr size_t WS_SATT   = 41728;              // 8192
constexpr size_t WS_AVGO   = 49920;              // 8192
constexpr size_t WS_MAXO   = 58112;              // 8192
constexpr size_t WS_SP     = 66304;              // 8192
constexpr size_t WS_PRE    = 74496;              // 2097152
constexpr size_t WS_T1B    = 2171648;            // bf16 t1 (4194304 floats)
constexpr size_t WS_T2B    = 6365952;            // bf16 t2
constexpr size_t WS_XB     = 10560256;           // bf16 x
constexpr size_t WS_W1B    = 11608832;
constexpr size_t WS_PWB    = 11739904;
constexpr size_t WS_YB     = 11870976;           // bf16 y
// total = 16065280 floats = 64.3 MB

__device__ __forceinline__ float gelu_exact(float v) {
    return 0.5f * v * (1.0f + erff(v * 0.70710678118654752440f));
}

__device__ __forceinline__ u16 f2bf(float f) {
    u32 u = __float_as_uint(f);
    u += 0x7fff + ((u >> 16) & 1);   // round-to-nearest-even
    return (u16)(u >> 16);
}

__device__ __forceinline__ float bf2f(u16 v) {
    return __uint_as_float(((u32)v) << 16);
}

// order-preserving float->u32 key: unsigned compare order == float order
__device__ __forceinline__ u32 fkey(float f) {
    u32 u = __float_as_uint(f);
    return (u & 0x80000000u) ? ~u : (u | 0x80000000u);
}
__device__ __forceinline__ float fkeyinv(u32 k) {
    return __uint_as_float((k & 0x80000000u) ? (k ^ 0x80000000u) : ~k);
}

// ---------------- K0: zero accumulators + cast fp32 -> bf16 for x, w1, pw ----------------
__global__ __launch_bounds__(256) void cvt_all_kernel(const float* __restrict__ x,
                                                      const float* __restrict__ w1,
                                                      const float* __restrict__ pw,
                                                      u16* __restrict__ xb,
                                                      u16* __restrict__ w1b,
                                                      u16* __restrict__ pwb,
                                                      float* __restrict__ acc_zero) {
    const int i = blockIdx.x * 256 + threadIdx.x;
    if (i < (int)WS_ACC_COUNT) acc_zero[i] = 0.f;   // 0x0 == fkey floor for max-keys too
    const float* src;
    u16* dst;
    int off;
    if (i < 524288)      { src = x;  dst = xb;  off = i; }
    else if (i < 589824) { src = w1; dst = w1b; off = i - 524288; }
    else                 { src = pw; dst = pwb; off = i - 589824; }
    const float4 v = *(const float4*)(src + (size_t)off * 4);
    uint2 o;
    o.x = ((u32)f2bf(v.x)) | ((u32)f2bf(v.y) << 16);
    o.y = ((u32)f2bf(v.z)) | ((u32)f2bf(v.w) << 16);
    *(uint2*)(dst + (size_t)off * 4) = o;
}

// ---------------- MFMA bf16 GEMM, K-unroll×2 double-buffered staging ----------------
// MBxNB tile. Per 64-k step: issue both 32-k chunks' global_load_lds, ONE barrier,
// MFMA both buffers, ONE barrier. Row stride stays 32 u16 (2-way bank alias = free).
// EPI 0 (gemm1): t = gelu(acc+bias); bf16 out via LDS-staged coalesced stores; col stats + gsum
// EPI 1 (gemm2): t = rowscale*acc + bias; fp32 out via LDS-staged coalesced stores; col stats
// Dyn LDS: 2*(MB*32 + NB*32)*2 bytes;  Cs staging aliases (≤ that size for both EPIs).
template<int KD, int EPI, int NS, int MB, int NB>
__global__ __launch_bounds__(256) void mfma_gemm_kernel(
    const u16* __restrict__ A,
    const u16* __restrict__ Bw,
    const float* __restrict__ bias,
    const float* __restrict__ rowscale,
    void* __restrict__ outv,
    float* __restrict__ csum,
    float* __restrict__ csq,
    float* __restrict__ gsum)
{
    constexpr int MI = MB / 32;
    constexpr int NJ = NB / 32;
    constexpr int ASZ = MB * 32;
    constexpr int BSZ = NB * 32;
    extern __shared__ u16 smem[];
    u16* As0 = smem;
    u16* As1 = smem + ASZ;
    u16* Bs0 = smem + 2 * ASZ;
    u16* Bs1 = smem + 2 * ASZ + BSZ;
    const int t = threadIdx.x;
    const int lane = t & 63;
    const int row0 = blockIdx.y * MB;
    const int col0 = blockIdx.x * NB;
    const int wv = t >> 6;
    const int wrow = (wv >> 1) * (MB / 2);
    const int wcol = (wv & 1) * (NB / 2);
    const int lm = lane & 15;
    const int lk8 = (lane >> 4) * 8;
    const int srow = t >> 2;
    const int scol = (t & 3) * 8;
    const u16* gA0 = A + (size_t)(row0 + srow) * KD + scol;
    const u16* gA1 = A + (size_t)(row0 + 64 + srow) * KD + scol;
    const u16* gB0 = Bw + (size_t)(col0 + srow) * KD + scol;
    const floatx4 zero = {0.f, 0.f, 0.f, 0.f};
    floatx4 acc[MI][NJ];
#pragma unroll
    for (int i = 0; i < MI; ++i)
#pragma unroll
        for (int j = 0; j < NJ; ++j) acc[i][j] = zero;

    for (int k0 = 0; k0 < KD; k0 += 64) {
        // chunk 0 -> buf0
        __builtin_amdgcn_global_load_lds(
            (const __attribute__((address_space(1))) void*)(gA0 + k0),
            (__attribute__((address_space(3))) void*)(As0 + t * 8), 16, 0, 0);
        if (MB == 128)
            __builtin_amdgcn_global_load_lds(
                (const __attribute__((address_space(1))) void*)(gA1 + k0),
                (__attribute__((address_space(3))) void*)(As0 + 2048 + t * 8), 16, 0, 0);
        __builtin_amdgcn_global_load_lds(
            (const __attribute__((address_space(1))) void*)(gB0 + k0),
            (__attribute__((address_space(3))) void*)(Bs0 + t * 8), 16, 0, 0);
        // chunk 1 -> buf1
        __builtin_amdgcn_global_load_lds(
            (const __attribute__((address_space(1))) void*)(gA0 + k0 + 32),
            (__attribute__((address_space(3))) void*)(As1 + t * 8), 16, 0, 0);
        if (MB == 128)
            __builtin_amdgcn_global_load_lds(
                (const __attribute__((address_space(1))) void*)(gA1 + k0 + 32),
                (__attribute__((address_space(3))) void*)(As1 + 2048 + t * 8), 16, 0, 0);
        __builtin_amdgcn_global_load_lds(
            (const __attribute__((address_space(1))) void*)(gB0 + k0 + 32),
            (__attribute__((address_space(3))) void*)(Bs1 + t * 8), 16, 0, 0);
        __syncthreads();
#pragma unroll
        for (int buf = 0; buf < 2; ++buf) {
            const u16* As = buf ? As1 : As0;
            const u16* Bs = buf ? Bs1 : Bs0;
            short8 af[MI], bf[NJ];
#pragma unroll
            for (int i = 0; i < MI; ++i)
                af[i] = *(const short8*)(As + (wrow + i * 16 + lm) * 32 + lk8);
#pragma unroll
            for (int j = 0; j < NJ; ++j)
                bf[j] = *(const short8*)(Bs + (wcol + j * 16 + lm) * 32 + lk8);
#pragma unroll
            for (int i = 0; i < MI; ++i)
#pragma unroll
                for (int j = 0; j < NJ; ++j)
                    acc[i][j] = __builtin_amdgcn_mfma_f32_16x16x32_bf16(af[i], bf[j], acc[i][j], 0, 0, 0);
        }
        __syncthreads();
    }

    float colsum[NJ], colsq[NJ];
#pragma unroll
    for (int j = 0; j < NJ; ++j) { colsum[j] = 0.f; colsq[j] = 0.f; }

    if (EPI == 0) {
        // stage bf16 tile in LDS (MB x NB u16), then coalesced stores
        u16* Cs = smem;
#pragma unroll
        for (int i = 0; i < MI; ++i) {
#pragma unroll
            for (int r = 0; r < 4; ++r) {
                const int lrow = wrow + i * 16 + (lane >> 4) * 4 + r;
#pragma unroll
                for (int j = 0; j < NJ; ++j) {
                    const int lcol = wcol + j * 16 + lm;
                    const float tv = gelu_exact(acc[i][j][r] + bias[col0 + lcol]);
                    Cs[lrow * NB + lcol] = f2bf(tv);
                    colsum[j] += tv;
                    colsq[j] = fmaf(tv, tv, colsq[j]);
                }
            }
        }
        __syncthreads();
        const int rr = t >> 1;
        const int hh = (t & 1) * 32;
        u16* outp = (u16*)outv + (size_t)(row0 + rr) * NS + col0 + hh;
#pragma unroll
        for (int k = 0; k < 4; ++k) {
            *(uint4*)(outp + k * 8) = *(const uint4*)(Cs + rr * NB + hh + k * 8);
        }
    } else {
        // stage fp32 tile in LDS (MB x NB floats), then coalesced stores
        float* Cs = (float*)smem;
#pragma unroll
        for (int i = 0; i < MI; ++i) {
#pragma unroll
            for (int r = 0; r < 4; ++r) {
                const int lrow = wrow + i * 16 + (lane >> 4) * 4 + r;
                const float rs = rowscale[row0 + lrow];
#pragma unroll
                for (int j = 0; j < NJ; ++j) {
                    const int lcol = wcol + j * 16 + lm;
                    const float tv = rs * acc[i][j][r] + bias[col0 + lcol];
                    Cs[lrow * NB + lcol] = tv;
                    colsum[j] += tv;
                    colsq[j] = fmaf(tv, tv, colsq[j]);
                }
            }
        }
        __syncthreads();
        const int rr = t >> 2;               // 4 threads/row, 64 B each
        const int hh = (t & 3) * 16;
        float* outp = (float*)outv + (size_t)(row0 + rr) * NS + col0 + hh;
#pragma unroll
        for (int k = 0; k < 4; ++k)
            *(float4*)(outp + k * 4) = *(const float4*)(Cs + rr * NB + hh + k * 4);
    }

    const int bb = (blockIdx.y * MB) >> 10;   // batch index
#pragma unroll
    for (int j = 0; j < NJ; ++j) {
        float s = colsum[j];
        float q = colsq[j];
        s += __shfl_xor(s, 16); s += __shfl_xor(s, 32);
        q += __shfl_xor(q, 16); q += __shfl_xor(q, 32);
        if (lane < 16) {
            const int c = col0 + wcol + j * 16 + lm;
            atomicAdd(&csum[c], s);
            atomicAdd(&csq[c], q);
            if (EPI == 0) atomicAdd(&gsum[bb * NS + c], s);
        }
    }
}

// ---------------- K4: dynamic kernel MLP + fused BN1 stats ----------------
__global__ __launch_bounds__(1024) void dynmlp_kernel(const float* __restrict__ chsum1,
                                                      const float* __restrict__ chsq1,
                                                      const float* __restrict__ gapsum,
                                                      const float* __restrict__ g1,
                                                      const float* __restrict__ be1,
                                                      const float* __restrict__ aw1,
                                                      const float* __restrict__ ab1,
                                                      const float* __restrict__ aw2,
                                                      const float* __restrict__ ab2,
                                                      float* __restrict__ scale1,
                                                      float* __restrict__ shift1,
                                                      float* __restrict__ kw) {
    const int b = blockIdx.x;
    const int t = threadIdx.x;
    const int wave = t >> 6, lane = t & 63;
    __shared__ float g[1024];
    __shared__ float h1[128];
    __shared__ float logits[12];
    {
        const float m = chsum1[t] * (1.0f / (float)M);
        const float var = chsq1[t] * (1.0f / (float)M) - m * m;
        const float rstd = rsqrtf(var + EPS);
        const float sc = rstd * g1[t];
        const float sh = be1[t] - m * sc;
        if (b == 0) { scale1[t] = sc; shift1[t] = sh; }
        g[t] = gapsum[b * C + t] * (1.0f / (float)P) * sc + sh;
    }
    __syncthreads();
#pragma unroll
    for (int k = 0; k < 8; ++k) {
        const int u = wave * 8 + k;
        const float4* wr = (const float4*)(aw1 + (size_t)u * C);
        float s = 0.f;
#pragma unroll
        for (int ch = 0; ch < 4; ++ch) {
            const float4 wv = wr[lane + 64 * ch];
            const float4 sv = *(const float4*)(g + 4 * lane + 256 * ch);
            s += wv.x * sv.x + wv.y * sv.y + wv.z * sv.z + wv.w * sv.w;
        }
#pragma unroll
        for (int off = 1; off < 64; off <<= 1) s += __shfl_xor(s, off);
        if (lane == 0) h1[u] = fmaxf(s + ab1[u], 0.f);
    }
    __syncthreads();
    if (wave < 9) {
        float s = aw2[wave * 128 + lane] * h1[lane]
                + aw2[wave * 128 + 64 + lane] * h1[64 + lane];
#pragma unroll
        for (int off = 1; off < 64; off <<= 1) s += __shfl_xor(s, off);
        if (lane == 0) logits[wave] = s + ab2[wave];
    }
    __syncthreads();
    if (t == 0) {
        float mx = logits[0];
        for (int i = 1; i < 9; ++i) mx = fmaxf(mx, logits[i]);
        float e[9], den = 0.f;
        for (int i = 0; i < 9; ++i) { e[i] = expf(logits[i] - mx); den += e[i]; }
        const float inv = 1.0f / den;
        for (int i = 0; i < 9; ++i) kw[b * 9 + i] = e[i] * inv;
    }
}

// ---------------- K5: dyn depthwise conv v3 — LDS-staged rows (R11-proven) ----------------
__global__ __launch_bounds__(256) void dwconv_kernel(const u16* __restrict__ t1b,
                                                     const float* __restrict__ scale1,
                                                     const float* __restrict__ shift1,
                                                     const float* __restrict__ kw,
                                                     u16* __restrict__ t2b,
                                                     float* __restrict__ chsum2,
                                                     float* __restrict__ chsq2,
                                                     float* __restrict__ bsum2,
                                                     u32* __restrict__ umax2,
                                                     u32* __restrict__ umaxn2) {
    __shared__ u16 rows[3 * 32 * 256];   // 48 KB: [r][w][ch]
    const int bh = blockIdx.y;
    const int b = bh >> 5;
    const int h = bh & 31;
    const int cq = blockIdx.x;
    const int t = threadIdx.x;

    const u16* gbase = t1b + (size_t)b * P * C + cq * 256;
#pragma unroll
    for (int i = 0; i < 12; ++i) {
        const int lin = i * 256 + t;
        const int chunk = lin >> 5;
        const int r = chunk >> 5;
        const int w = chunk & 31;
        const int off8 = (lin & 31) * 8;
        const int hr = h + r - 1;
        uint4 v = {0u, 0u, 0u, 0u};
        if (hr >= 0 && hr < H)
            v = *(const uint4*)(gbase + (size_t)(hr * W + w) * C + off8);
        *(uint4*)(&rows[chunk * 256 + off8]) = v;
    }
    __syncthreads();

    const int c = t;
    const int gc = cq * 256 + c;
    float k[9];
#pragma unroll
    for (int i = 0; i < 9; ++i) k[i] = kw[b * 9 + i];
    const float sc = scale1[gc];
    const float sh = shift1[gc];
    const bool rok[3] = { h > 0, true, h < H - 1 };

    float s = 0.f, q = 0.f, mx = -INFINITY, mn = INFINITY;
    for (int w = 0; w < W; ++w) {
        float acc = 0.f;
#pragma unroll
        for (int ri = 0; ri < 3; ++ri) {
            if (!rok[ri]) continue;
            const u16* rp = rows + (ri * 32) * 256 + c;
            if (w > 0)
                acc = fmaf(k[ri * 3 + 0], fmaf(bf2f(rp[(w - 1) * 256]), sc, sh), acc);
            acc = fmaf(k[ri * 3 + 1], fmaf(bf2f(rp[w * 256]), sc, sh), acc);
            if (w < W - 1)
                acc = fmaf(k[ri * 3 + 2], fmaf(bf2f(rp[(w + 1) * 256]), sc, sh), acc);
        }
        const float y = gelu_exact(acc);
        t2b[((size_t)b * P + h * W + w) * C + gc] = f2bf(y);
        s += y;
        q = fmaf(y, y, q);
        mx = fmaxf(mx, y);
        mn = fminf(mn, y);
    }
    atomicAdd(&chsum2[gc], s);
    atomicAdd(&chsq2[gc], q);
    atomicAdd(&bsum2[b * C + gc], s);
    atomicMax(&umax2[b * C + gc], fkey(mx));
    atomicMax(&umaxn2[b * C + gc], fkey(-mn));
}

// ---------------- K8: channel attention + O(1) BN2 finalize ----------------
__global__ __launch_bounds__(1024) void chatt_kernel(const float* __restrict__ chsum2,
                                                     const float* __restrict__ chsq2,
                                                     const float* __restrict__ bsum2,
                                                     const u32* __restrict__ umax2,
                                                     const u32* __restrict__ umaxn2,
                                                     const float* __restrict__ g2,
                                                     const float* __restrict__ be2,
                                                     const float* __restrict__ caw1,
                                                     const float* __restrict__ caw2,
                                                     float* __restrict__ scale2,
                                                     float* __restrict__ shift2,
                                                     float* __restrict__ s_att) {
    const int b = blockIdx.x;
    const int t = threadIdx.x;          // channel
    const int wave = t >> 6, lane = t & 63;
    __shared__ float la[1024], lx[1024], ha[64], hm[64];
    {
        const float m = chsum2[t] * (1.0f / (float)M);
        const float var = chsq2[t] * (1.0f / (float)M) - m * m;
        const float rstd = rsqrtf(var + EPS);
        const float sc = rstd * g2[t];
        const float sh = be2[t] - m * sc;
        if (b == 0) { scale2[t] = sc; shift2[t] = sh; }
        la[t] = bsum2[b * C + t] * (1.0f / (float)P) * sc + sh;
        const float mx = fkeyinv(umax2[b * C + t]);
        const float mn = -fkeyinv(umaxn2[b * C + t]);
        lx[t] = (sc >= 0.f ? mx : mn) * sc + sh;
    }
    __syncthreads();
#pragma unroll
    for (int k = 0; k < 8; ++k) {
        const int u = wave * 8 + k;
        const int row = u & 63;
        const float* src = (u < 64) ? la : lx;
        const float4* wr = (const float4*)(caw1 + (size_t)row * C);
        float s = 0.f;
#pragma unroll
        for (int ch = 0; ch < 4; ++ch) {
            const float4 wv = wr[lane + 64 * ch];
            const float4 sv = *(const float4*)(src + 4 * lane + 256 * ch);
            s += wv.x * sv.x + wv.y * sv.y + wv.z * sv.z + wv.w * sv.w;
        }
#pragma unroll
        for (int off = 1; off < 64; off <<= 1) s += __shfl_xor(s, off);
        if (lane == 0) {
            s = fmaxf(s, 0.f);
            if (u < 64) ha[row] = s; else hm[row] = s;
        }
    }
    __syncthreads();
    {
        const float4* w2 = (const float4*)(caw2 + (size_t)t * 64);
        float s = 0.f;
#pragma unroll
        for (int j = 0; j < 16; ++j) {
            const float4 wv = w2[j];
            s += wv.x * (ha[j * 4 + 0] + hm[j * 4 + 0]);
            s += wv.y * (ha[j * 4 + 1] + hm[j * 4 + 1]);
            s += wv.z * (ha[j * 4 + 2] + hm[j * 4 + 2]);
            s += wv.w * (ha[j * 4 + 3] + hm[j * 4 + 3]);
        }
        s_att[b * C + t] = 1.0f / (1.0f + expf(-s));
    }
}

// ---------------- K9: y = s_att*bn2(t2) -> bf16 yb + per-row avg/max ----------------
__global__ __launch_bounds__(256) void yq_kernel(const u16* __restrict__ t2b,
                                                 const float* __restrict__ scale2,
                                                 const float* __restrict__ shift2,
                                                 const float* __restrict__ s_att,
                                                 u16* __restrict__ yb,
                                                 float* __restrict__ avg_o,
                                                 float* __restrict__ max_o) {
    const int row = blockIdx.x;       // b*P + p
    const int b = row >> 10;
    const int t = threadIdx.x;
    const int c0 = t * 4;
    const uint2 vv = *(const uint2*)(t2b + (size_t)row * C + c0);
    const float v0 = bf2f((u16)(vv.x & 0xffff));
    const float v1 = bf2f((u16)(vv.x >> 16));
    const float v2 = bf2f((u16)(vv.y & 0xffff));
    const float v3 = bf2f((u16)(vv.y >> 16));
    const float4 sc = *(const float4*)(scale2 + c0);
    const float4 sh = *(const float4*)(shift2 + c0);
    const float4 sa = *(const float4*)(s_att + (size_t)b * C + c0);
    const float y0 = fmaf(v0, sc.x, sh.x) * sa.x;
    const float y1 = fmaf(v1, sc.y, sh.y) * sa.y;
    const float y2 = fmaf(v2, sc.z, sh.z) * sa.z;
    const float y3 = fmaf(v3, sc.w, sh.w) * sa.w;
    uint2 o;
    o.x = ((u32)f2bf(y0)) | ((u32)f2bf(y1) << 16);
    o.y = ((u32)f2bf(y2)) | ((u32)f2bf(y3) << 16);
    *(uint2*)(yb + (size_t)row * C + c0) = o;
    float s = (y0 + y1) + (y2 + y3);
    float mx = fmaxf(fmaxf(y0, y1), fmaxf(y2, y3));
#pragma unroll
    for (int off = 32; off > 0; off >>= 1) {
        s += __shfl_down(s, off);
        mx = fmaxf(mx, __shfl_down(mx, off));
    }
    __shared__ float ss[4], sm[4];
    const int wave = t >> 6, lane = t & 63;
    if (lane == 0) { ss[wave] = s; sm[wave] = mx; }
    __syncthreads();
    if (t == 0) {
        const float S = ss[0] + ss[1] + ss[2] + ss[3];
        const float Mx = fmaxf(fmaxf(sm[0], sm[1]), fmaxf(sm[2], sm[3]));
        avg_o[row] = S * (1.0f / (float)C);
        max_o[row] = Mx;
    }
}

// ---------------- K10: 7x7 spatial conv + sigmoid (1 pixel/thread) ----------------
__global__ __launch_bounds__(1024) void spconv_kernel(const float* __restrict__ avg_o,
                                                      const float* __restrict__ max_o,
                                                      const float* __restrict__ sw,
                                                      const float* __restrict__ sb,
                                                      float* __restrict__ sp) {
    const int b = blockIdx.x;
    const int t = threadIdx.x;
    __shared__ float pa[P], pm[P], wsh[98];
    pa[t] = avg_o[b * P + t];
    pm[t] = max_o[b * P + t];
    if (t < 98) wsh[t] = sw[t];
    const float sbv = sb[0];
    __syncthreads();
    const int h = t >> 5, w = t & 31;
    float acc = sbv;
#pragma unroll
    for (int i = 0; i < 7; ++i) {
        const int hh = h + i - 3;
        if (hh < 0 || hh >= H) continue;
#pragma unroll
        for (int j = 0; j < 7; ++j) {
            const int ww = w + j - 3;
            if (ww < 0 || ww >= W) continue;
            const int pidx = hh * W + ww;
            acc = fmaf(wsh[i * 7 + j], pa[pidx], acc);
            acc = fmaf(wsh[49 + i * 7 + j], pm[pidx], acc);
        }
    }
    sp[b * P + t] = 1.0f / (1.0f + expf(-acc));
}

// ---------------- K15: final residual add + fused BN3 stats ----------------
__global__ __launch_bounds__(256) void final_kernel(const float* __restrict__ x,
                                                    const float* __restrict__ pre,
                                                    const float* __restrict__ chsum3,
                                                    const float* __restrict__ chsq3,
                                                    const float* __restrict__ g3,
                                                    const float* __restrict__ be3,
                                                    float* __restrict__ out) {
    __shared__ float lsc[256], lsh[256];
    const int t = threadIdx.x;
    {
        const float m = chsum3[t] * (1.0f / (float)M);
        const float var = chsq3[t] * (1.0f / (float)M) - m * m;
        const float rstd = rsqrtf(var + EPS);
        const float sc = rstd * g3[t];
        lsc[t] = sc;
        lsh[t] = be3[t] - m * sc;
    }
    __syncthreads();
    const int i = blockIdx.x * 256 + t;   // float4 index
    const int e = i * 4;
    const int d = e & 255;
    const float4 xv = *(const float4*)(x + e);
    const float4 pv = *(const float4*)(pre + e);
    const float4 sc = *(const float4*)(lsc + d);
    const float4 sh = *(const float4*)(lsh + d);
    float4 o;
    o.x = xv.x + fmaf(pv.x, sc.x, sh.x);
    o.y = xv.y + fmaf(pv.y, sc.y, sh.y);
    o.z = xv.z + fmaf(pv.z, sc.z, sh.z);
    o.w = xv.w + fmaf(pv.w, sc.w, sh.w);
    *(float4*)(out + e) = o;
}

extern "C" void kernel_launch(void* const* d_in, const int* in_sizes, int n_in,
                              void* d_out, int out_size, void* d_ws, size_t ws_size,
                              hipStream_t stream) {
    const float* x    = (const float*)d_in[0];
    const float* w1   = (const float*)d_in[1];
    const float* b1   = (const float*)d_in[2];
    const float* g1   = (const float*)d_in[3];
    const float* be1  = (const float*)d_in[4];
    const float* aw1  = (const float*)d_in[5];
    const float* ab1  = (const float*)d_in[6];
    const float* aw2  = (const float*)d_in[7];
    const float* ab2  = (const float*)d_in[8];
    const float* g2   = (const float*)d_in[9];
    const float* be2  = (const float*)d_in[10];
    const float* caw1 = (const float*)d_in[11];
    const float* caw2 = (const float*)d_in[12];
    const float* pw   = (const float*)d_in[13];
    const float* pb   = (const float*)d_in[14];
    const float* g3   = (const float*)d_in[15];
    const float* be3  = (const float*)d_in[16];
    const float* sw   = (const float*)d_in[17];
    const float* sb   = (const float*)d_in[18];
    float* out = (float*)d_out;
    float* ws = (float*)d_ws;

    float* chsum1  = ws + WS_CHSUM1;
    float* chsq1   = ws + WS_CHSQ1;
    float* gapsum  = ws + WS_GAPSUM;
    float* chsum3  = ws + WS_CHSUM3;
    float* chsq3   = ws + WS_CHSQ3;
    float* chsum2  = ws + WS_CHSUM2;
    float* chsq2   = ws + WS_CHSQ2;
    float* bsum2   = ws + WS_BSUM2;
    u32*   umax2   = (u32*)(ws + WS_UMAX2);
    u32*   umaxn2  = (u32*)(ws + WS_UMAXN2);
    float* scale1  = ws + WS_SCALE1;
    float* shift1  = ws + WS_SHIFT1;
    float* kw      = ws + WS_KW;
    float* scale2  = ws + WS_SCALE2;
    float* shift2  = ws + WS_SHIFT2;
    float* s_att   = ws + WS_SATT;
    float* avg_o   = ws + WS_AVGO;
    float* max_o   = ws + WS_MAXO;
    float* sp      = ws + WS_SP;
    float* pre     = ws + WS_PRE;
    u16* t1b = (u16*)(ws + WS_T1B);
    u16* t2b = (u16*)(ws + WS_T2B);
    u16* xb  = (u16*)(ws + WS_XB);
    u16* w1b = (u16*)(ws + WS_W1B);
    u16* pwb = (u16*)(ws + WS_PWB);
    u16* yb  = (u16*)(ws + WS_YB);

    // K0: zero accumulators + all casts in one launch
    cvt_all_kernel<<<dim3(2560), 256, 0, stream>>>(x, w1, pw, xb, w1b, pwb, ws);
    // K1: expand GEMM (128x64 tile, K-unroll x2 dbuf). Dyn LDS = 2*(128*32+64*32)*2 = 24576 B
    mfma_gemm_kernel<256, 0, C, 128, 64><<<dim3(C / 64, M / 128), 256, 24576, stream>>>(
        xb, w1b, b1, nullptr, t1b, chsum1, chsq1, gapsum);
    // K4: BN1 stats + gap + dynamic kernel weights (fused)
    dynmlp_kernel<<<dim3(B), 1024, 0, stream>>>(chsum1, chsq1, gapsum, g1, be1,
                                                aw1, ab1, aw2, ab2, scale1, shift1, kw);
    // K5: depthwise conv v3 (LDS-staged rows, 1024 blocks) + GELU -> bf16 t2, BN2 atomics
    dwconv_kernel<<<dim3(4, B * H), 256, 0, stream>>>(t1b, scale1, shift1, kw, t2b,
                                                      chsum2, chsq2, bsum2, umax2, umaxn2);
    // K8: BN2 finalize (O(1)/thread) + channel attention
    chatt_kernel<<<dim3(B), 1024, 0, stream>>>(chsum2, chsq2, bsum2, umax2, umaxn2,
                                               g2, be2, caw1, caw2, scale2, shift2, s_att);
    // K9: y quantize + spatial stats
    yq_kernel<<<dim3(M), 256, 0, stream>>>(t2b, scale2, shift2, s_att, yb, avg_o, max_o);
    // K10: 7x7 conv + sigmoid
    spconv_kernel<<<dim3(B), 1024, 0, stream>>>(avg_o, max_o, sw, sb, sp);
    // K12: project GEMM (64x64 tile, K-unroll x2 dbuf, LDS-staged fp32 stores).
    //      Dyn LDS = 2*(64*32+64*32)*2 = 16384 B
    mfma_gemm_kernel<1024, 1, D, 64, 64><<<dim3(D / 64, M / 64), 256, 16384, stream>>>(
        yb, pwb, pb, sp, pre, chsum3, chsq3, nullptr);
    // K15: BN3 stats + final residual add (fused)
    final_kernel<<<dim3((M * D / 4) / 256), 256, 0, stream>>>(x, pre, chsum3, chsq3, g3, be3, out);
}